// Round 3
// baseline (2296.040 us; speedup 1.0000x reference)
//
#include <hip/hip_runtime.h>

// Problem constants (fixed by the reference file)
#define NPTS 524288
#define NUMC 128
#define FD   8
#define NBLK 2048          // NPTS / 256
#define ITERS 5

// k_sums LDS ring: RING slots x 8 features x CSZ members
#define CSZ   512          // members per chunk per feature
#define FCOL  516          // column stride in floats: 2064B, 16B-aligned; 516%32=4 -> lanes 0..7 bank-disjoint
#define SLOTF (FD * FCOL)  // 4128 floats per slot
#define RING  3            // 49536 B LDS; 2-chunk DMA lead ~4000 cyc >> 900 cyc miss

static_assert(NPTS == NBLK * 256, "grid must tile N exactly");

#define WAITVM(N) asm volatile("s_waitcnt vmcnt(" #N ")" ::: "memory")

__global__ void k_init(const float* __restrict__ cin, float* __restrict__ cen,
                       int* __restrict__ flag, int* __restrict__ cnt_inr,
                       int* __restrict__ done) {
    int t = blockIdx.x * 256 + threadIdx.x;
    if (t < NUMC * FD) cen[t] = cin[t];
    if (t < NUMC) cnt_inr[t] = 0;
    if (t == 0) { *flag = 0; *done = 0; }
}

// Pass A: per-center count of points with sqrt(dx^2+dy^2) <= 0.32
__global__ void k_count(const float* __restrict__ data, const float* __restrict__ cen,
                        int* __restrict__ cnt_inr, const int* __restrict__ flag) {
    if (*flag) return;
    __shared__ float cx[NUMC], cy[NUMC];
    __shared__ int hist[NUMC];
    int tid = threadIdx.x;
    if (tid < NUMC) { cx[tid] = cen[tid * FD]; cy[tid] = cen[tid * FD + 1]; hist[tid] = 0; }
    __syncthreads();
    size_t j = (size_t)blockIdx.x * 256 + tid;
    float2 p = *(const float2*)(data + j * FD);
    int lane = tid & 63;
    for (int i = 0; i < NUMC; i++) {
        float dx = __fsub_rn(p.x, cx[i]);
        float dy = __fsub_rn(p.y, cy[i]);
        float s  = __fadd_rn(__fmul_rn(dx, dx), __fmul_rn(dy, dy));
        bool in  = (__fsqrt_rn(s) <= 0.32f);
        unsigned long long m = __ballot(in);
        if (lane == 0 && m) atomicAdd(&hist[i], __popcll(m));
    }
    __syncthreads();
    if (tid < NUMC && hist[tid]) atomicAdd(&cnt_inr[tid], hist[tid]);
}

// Pass B: sequential-per-center assignment chain with the freeze quirk.
__global__ void k_assign(const float* __restrict__ data, const float* __restrict__ cen,
                         const int* __restrict__ cnt_inr, int* __restrict__ labels,
                         int* __restrict__ blockhist, const int* __restrict__ flag) {
    if (*flag) return;
    __shared__ float C[NUMC * FD];
    __shared__ int enough[NUMC];
    __shared__ int hist[NUMC];
    int tid = threadIdx.x;
    for (int e = tid; e < NUMC * FD; e += 256) C[e] = cen[e];
    if (tid < NUMC) { enough[tid] = (cnt_inr[tid] > 1); hist[tid] = 0; }
    __syncthreads();
    size_t j = (size_t)blockIdx.x * 256 + tid;
    float4 a = *(const float4*)(data + j * FD);
    float4 b = *(const float4*)(data + j * FD + 4);
    float x[8] = {a.x, a.y, a.z, a.w, b.x, b.y, b.z, b.w};
    int lab = -1;
    float dval = 1000.0f;
    for (int i = 0; i < NUMC; i++) {
        const float* c = &C[i * FD];
        float dx = __fsub_rn(x[0], c[0]);
        float dy = __fsub_rn(x[1], c[1]);
        float s  = __fadd_rn(__fmul_rn(dx, dx), __fmul_rn(dy, dy));
        float sp = __fsqrt_rn(s);
        if (sp <= 0.32f && enough[i]) {
            float t0 = __fadd_rn(__fsub_rn(x[0], c[0]), 1e-6f);
            float ss = __fmul_rn(t0, t0);
            #pragma unroll
            for (int f = 1; f < 8; f++) {
                float tf = __fadd_rn(__fsub_rn(x[f], c[f]), 1e-6f);
                ss = __fadd_rn(ss, __fmul_rn(tf, tf));
            }
            float D = __fsqrt_rn(ss);
            if (D < dval) { dval = D; lab = i; }
            else break;   // reference sets dval=0 -> frozen forever
        }
    }
    labels[j] = lab;
    if (lab >= 0) atomicAdd(&hist[lab], 1);
    __syncthreads();
    if (tid < NUMC) blockhist[tid * NBLK + blockIdx.x] = hist[tid];
}

// Per-cluster exclusive scan over the 2048 block counts.
// Folded k_base: the last block to finish computes cbase from ctot
// (threadfence + done-counter pattern), saving a 1-block launch per iter.
__global__ void k_scan(int* __restrict__ blockhist, int* __restrict__ ctot,
                       int* __restrict__ cbase, int* __restrict__ done,
                       const int* __restrict__ flag) {
    if (*flag) return;
    int c = blockIdx.x, tid = threadIdx.x;
    __shared__ int ts[256];
    __shared__ int amLast;
    int base = c * NBLK + tid * 8;
    int v[8], s = 0;
    #pragma unroll
    for (int u = 0; u < 8; u++) { v[u] = blockhist[base + u]; s += v[u]; }
    ts[tid] = s;
    __syncthreads();
    for (int off = 1; off < 256; off <<= 1) {
        int t = (tid >= off) ? ts[tid - off] : 0;
        __syncthreads();
        ts[tid] += t;
        __syncthreads();
    }
    int run = (tid == 0) ? 0 : ts[tid - 1];
    #pragma unroll
    for (int u = 0; u < 8; u++) { int t = v[u]; blockhist[base + u] = run; run += t; }
    if (tid == 255) {
        ctot[c] = run;
        __threadfence();
        amLast = (atomicAdd(done, 1) == NUMC - 1);
    }
    __syncthreads();
    if (amLast) {
        __threadfence();
        int val = (tid < NUMC) ? ctot[tid] : 0;
        ts[tid] = val;
        __syncthreads();
        for (int off = 1; off < NUMC; off <<= 1) {
            int t2 = (tid >= off) ? ts[tid - off] : 0;
            __syncthreads();
            ts[tid] += t2;
            __syncthreads();
        }
        if (tid < NUMC) cbase[tid] = ts[tid] - val;   // exclusive prefix
        if (tid == NUMC - 1) cbase[NUMC] = ts[tid];   // total assigned
        if (tid == 0) *done = 0;                      // reset for next iter
    }
}

// Fused stable scatter + feature-major materialization: thread j computes its
// stable position and writes its 8 features directly into the sorted columns.
__global__ void k_scatter(const float* __restrict__ data, const int* __restrict__ labels,
                          const int* __restrict__ blockhist, const int* __restrict__ cbase,
                          float* __restrict__ sorted, const int* __restrict__ flag) {
    if (*flag) return;
    __shared__ int sl[256];
    int tid = threadIdx.x;
    int j = blockIdx.x * 256 + tid;
    sl[tid] = labels[j];
    __syncthreads();
    int c = sl[tid];
    if (c >= 0) {
        int rank = 0;
        for (int t = 0; t < tid; t++) rank += (sl[t] == c);
        int pos = cbase[c] + blockhist[c * NBLK + blockIdx.x] + rank;
        float4 a = *(const float4*)(data + (size_t)j * FD);
        float4 b = *(const float4*)(data + (size_t)j * FD + 4);
        sorted[(size_t)0 * NPTS + pos] = a.x;
        sorted[(size_t)1 * NPTS + pos] = a.y;
        sorted[(size_t)2 * NPTS + pos] = a.z;
        sorted[(size_t)3 * NPTS + pos] = a.w;
        sorted[(size_t)4 * NPTS + pos] = b.x;
        sorted[(size_t)5 * NPTS + pos] = b.y;
        sorted[(size_t)6 * NPTS + pos] = b.z;
        sorted[(size_t)7 * NPTS + pos] = b.w;
    }
}

// Stage one 512-member chunk (all 8 features) into an LDS ring slot via async
// DMA: 16 x global_load_lds(16B/lane), no VGPR cost.
__device__ __forceinline__ void stage_chunk(const float* __restrict__ srt, int baseA,
                                            int t, int slot, float* sbuf, int lane) {
    const float* g0 = srt + (size_t)baseA + (size_t)t * CSZ + lane * 4;
    float* l0 = sbuf + slot * SLOTF;
    #pragma unroll
    for (int f = 0; f < FD; f++) {
        __builtin_amdgcn_global_load_lds(
            (const __attribute__((address_space(1))) void*)(g0 + (size_t)f * NPTS),
            (__attribute__((address_space(3))) void*)(l0 + f * FCOL),
            16, 0, 0);
        __builtin_amdgcn_global_load_lds(
            (const __attribute__((address_space(1))) void*)(g0 + (size_t)f * NPTS + 256),
            (__attribute__((address_space(3))) void*)(l0 + f * FCOL + 256),
            16, 0, 0);
    }
}

#define ADD4(v) { acc = __fadd_rn(acc, (v).x); acc = __fadd_rn(acc, (v).y); \
                  acc = __fadd_rn(acc, (v).z); acc = __fadd_rn(acc, (v).w); }

// Exact sequential fp32 segment sums: one wave per cluster. Continuous
// software pipeline across chunk boundaries. q-ring depth 16 (was 32):
// lgkmcnt is 4-bit (max 15) on gfx9-lineage, so a 32-deep ds_read ring
// forces inexpressible waits (clamp to lgkmcnt(15) -> forced drains); with
// depth 16 the consume-wait is exactly lgkmcnt(15), already satisfied.
// Add order identical to the reference scatter-add -> bit-exact.
__global__ void __launch_bounds__(64) k_sums(const float* __restrict__ sorted,
                       const int* __restrict__ cbase, const int* __restrict__ ctot,
                       float* __restrict__ sums, const int* __restrict__ flag) {
    if (*flag) return;
    __shared__ float sbuf[RING * SLOTF];
    int c = blockIdx.x;
    int lane = threadIdx.x;
    int m = ctot[c], base = cbase[c];
    float acc = 0.0f;
    const float* col = sorted + (size_t)lane * NPTS + base;   // lane<8 chain column

    int A = (4 - (base & 3)) & 3;          // scalar prologue to 16B alignment
    if (A > m) A = m;
    if (lane < FD)
        for (int k = 0; k < A; k++) acc = __fadd_rn(acc, col[k]);

    int baseA = base + A;
    int nch = (m - A) / CSZ;               // full 512-member chunks

    int pre = nch < RING ? nch : RING;
    for (int t = 0; t < pre; t++) stage_chunk(sorted, baseA, t, t, sbuf, lane);

    float4 q[16];
    if (nch > 0) {
        // wait for chunk 0's DMA, preload its first 16 float4s into the ring
        if (nch >= 3) { WAITVM(32); } else if (nch == 2) { WAITVM(16); } else { WAITVM(0); }
        if (lane < FD) {
            const float4* lv0 = (const float4*)(sbuf + lane * FCOL);
            #pragma unroll
            for (int d = 0; d < 16; d++) q[d] = lv0[d];
        }
    }

    int slot = 0;
    for (int t = 0; t < nch; t++) {
        if (t >= 1 && t + 2 < nch)
            stage_chunk(sorted, baseA, t + 2, slot == 0 ? 2 : slot - 1, sbuf, lane);
        const float4* lv = (const float4*)(sbuf + slot * SLOTF + lane * FCOL);
        if (lane < FD) {
            #pragma unroll 16
            for (int b = 0; b < 112; b++) {
                float4 v = q[b & 15];
                ADD4(v);
                q[b & 15] = lv[b + 16];
            }
        }
        int nslot = (slot == RING - 1) ? 0 : slot + 1;
        if (t + 1 < nch) {
            // chunk t+1's DMA must be complete before reading its LDS slot:
            // outstanding beyond t+1 is chunk t+2 (16 loads) if staged.
            if (t + 2 < nch) { WAITVM(16); } else { WAITVM(0); }
            if (lane < FD) {
                const float4* lvn = (const float4*)(sbuf + nslot * SLOTF + lane * FCOL);
                #pragma unroll
                for (int b = 112; b < 128; b++) {
                    float4 v = q[b & 15];
                    ADD4(v);
                    q[b & 15] = lvn[b - 112];
                }
            }
        } else {
            if (lane < FD) {
                #pragma unroll
                for (int b = 112; b < 128; b++) { float4 v = q[b & 15]; ADD4(v); }
            }
        }
        slot = nslot;
    }

    // tail: members [A + nch*CSZ, m) from global, float4 depth-16 pipe (aligned)
    if (lane < FD) {
        int start = A + nch * CSZ;
        int rem = m - start;
        const float* tcol = col + start;
        int tv = rem >> 2;
        const float4* tvp = (const float4*)tcol;
        float4 tb[16];
        #pragma unroll
        for (int d = 0; d < 16; d++) if (d < tv) tb[d] = tvp[d];
        int u = 0;
        for (; u + 32 <= tv; u += 16) {
            #pragma unroll
            for (int d = 0; d < 16; d++) {
                float4 v = tb[d];
                ADD4(v);
                tb[d] = tvp[u + 16 + d];
            }
        }
        #pragma unroll
        for (int d = 0; d < 16; d++) {
            if (u + d < tv) {
                float4 v = tb[d];
                ADD4(v);
                if (u + 16 + d < tv) tb[d] = tvp[u + 16 + d];
            }
        }
        u += 16;
        #pragma unroll
        for (int d = 0; d < 16; d++) {
            if (u + d < tv) { float4 v = tb[d]; ADD4(v); }
        }
        for (int k = tv << 2; k < rem; k++) acc = __fadd_rn(acc, tcol[k]);
        sums[c * FD + lane] = acc;
    }
}

// Center update + convergence flag (1 block); also zeroes cnt_inr for the
// next iteration (replaces the separate k_zero launch).
__global__ void k_update(float* __restrict__ cen, const float* __restrict__ sums,
                         const int* __restrict__ ctot, int* __restrict__ flag,
                         int* __restrict__ cnt_inr) {
    if (*flag) return;
    __shared__ float red[256];
    int tid = threadIdx.x;
    if (tid < NUMC) cnt_inr[tid] = 0;
    float sq = 0.0f;
    float newv[4];
    int   eidx[4];
    int ne = 0;
    for (int e = tid; e < NUMC * FD; e += 256) {
        int c = e >> 3;
        float oldv = cen[e];
        float cntf = (float)ctot[c];
        float mean = __fdiv_rn(sums[e], fmaxf(cntf, 1.0f));
        float nc = (cntf > 0.0f) ? mean : oldv;
        float d = __fsub_rn(nc, oldv);
        sq = __fadd_rn(sq, __fmul_rn(d, d));
        newv[ne] = nc; eidx[ne] = e; ne++;
    }
    red[tid] = sq;
    __syncthreads();
    for (int off = 128; off > 0; off >>= 1) {
        if (tid < off) red[tid] += red[tid + off];
        __syncthreads();
    }
    for (int u = 0; u < ne; u++) cen[eidx[u]] = newv[u];
    if (tid == 0) {
        float diff = __fsqrt_rn(red[0]);
        if (diff < 1e-4f) *flag = 1;
    }
}

// Finalize: labels staged as int32 in d_out[0..N); convert to float, append centers.
__global__ void k_finish(float* __restrict__ out, const float* __restrict__ cen) {
    size_t i = (size_t)blockIdx.x * 256 + threadIdx.x;
    if (i < NPTS) {
        int v = ((const int*)out)[i];
        out[i] = (float)v;
    } else if (i < NPTS + NUMC * FD) {
        out[i] = cen[i - NPTS];
    }
}

extern "C" void kernel_launch(void* const* d_in, const int* in_sizes, int n_in,
                              void* d_out, int out_size, void* d_ws, size_t ws_size,
                              hipStream_t stream) {
    const float* data = (const float*)d_in[0];
    const float* cen0 = (const float*)d_in[1];
    float* out = (float*)d_out;
    char* ws = (char*)d_ws;

    float* wcen   = (float*)(ws + 0);
    int*   flag   = (int*)(ws + 4096);
    int*   cntinr = (int*)(ws + 8192);
    int*   ctot   = (int*)(ws + 8704);
    int*   cbase  = (int*)(ws + 9216);    // 129 ints
    float* sums   = (float*)(ws + 10240);
    int*   done   = (int*)(ws + 14336);
    int*   bh     = (int*)(ws + 16384);
    float* sorted = (float*)(ws + 16384 + (size_t)NUMC * NBLK * 4);
    int*   labels = (int*)d_out;   // staged as int32, converted by k_finish

    k_init<<<4, 256, 0, stream>>>(cen0, wcen, flag, cntinr, done);
    for (int it = 0; it < ITERS; ++it) {
        k_count  <<<NBLK, 256, 0, stream>>>(data, wcen, cntinr, flag);
        k_assign <<<NBLK, 256, 0, stream>>>(data, wcen, cntinr, labels, bh, flag);
        k_scan   <<<NUMC, 256, 0, stream>>>(bh, ctot, cbase, done, flag);
        k_scatter<<<NBLK, 256, 0, stream>>>(data, labels, bh, cbase, sorted, flag);
        k_sums   <<<NUMC, 64, 0, stream>>>(sorted, cbase, ctot, sums, flag);
        k_update <<<1, 256, 0, stream>>>(wcen, sums, ctot, flag, cntinr);
    }
    k_finish<<<(NPTS + NUMC * FD + 255) / 256, 256, 0, stream>>>(out, wcen);
}

// Round 4
// 2089.458 us; speedup vs baseline: 1.0989x; 1.0989x over previous
//
#include <hip/hip_runtime.h>

// Problem constants (fixed by the reference file)
#define NPTS 524288
#define NUMC 128
#define FD   8
#define NBLK 2048          // NPTS / 256
#define ITERS 5

// k_sums LDS ring: RING slots x 8 features x CSZ members
#define CSZ   512          // members per chunk per feature
#define FCOL  516          // column stride in floats: 2064B, 16B-aligned; 516%32=4 -> lanes 0..7 bank-disjoint
#define SLOTF (FD * FCOL)  // 4128 floats per slot
#define RING  3            // 49536 B LDS; 2-chunk DMA lead ~4000 cyc >> 900 cyc miss

static_assert(NPTS == NBLK * 256, "grid must tile N exactly");

#define WAITVM(N) asm volatile("s_waitcnt vmcnt(" #N ")" ::: "memory")

__global__ void k_init(const float* __restrict__ cin, float* __restrict__ cen,
                       int* __restrict__ flag, int* __restrict__ cnt_inr,
                       int* __restrict__ done) {
    int t = blockIdx.x * 256 + threadIdx.x;
    if (t < NUMC * FD) cen[t] = cin[t];
    if (t < NUMC) cnt_inr[t] = 0;
    if (t == 0) { *flag = 0; *done = 0; }
}

// Pass A: per-center count of points with sqrt(dx^2+dy^2) <= 0.32
__global__ void k_count(const float* __restrict__ data, const float* __restrict__ cen,
                        int* __restrict__ cnt_inr, const int* __restrict__ flag) {
    if (*flag) return;
    __shared__ float cx[NUMC], cy[NUMC];
    __shared__ int hist[NUMC];
    int tid = threadIdx.x;
    if (tid < NUMC) { cx[tid] = cen[tid * FD]; cy[tid] = cen[tid * FD + 1]; hist[tid] = 0; }
    __syncthreads();
    size_t j = (size_t)blockIdx.x * 256 + tid;
    float2 p = *(const float2*)(data + j * FD);
    int lane = tid & 63;
    for (int i = 0; i < NUMC; i++) {
        float dx = __fsub_rn(p.x, cx[i]);
        float dy = __fsub_rn(p.y, cy[i]);
        float s  = __fadd_rn(__fmul_rn(dx, dx), __fmul_rn(dy, dy));
        bool in  = (__fsqrt_rn(s) <= 0.32f);
        unsigned long long m = __ballot(in);
        if (lane == 0 && m) atomicAdd(&hist[i], __popcll(m));
    }
    __syncthreads();
    if (tid < NUMC && hist[tid]) atomicAdd(&cnt_inr[tid], hist[tid]);
}

// Pass B: sequential-per-center assignment chain with the freeze quirk.
__global__ void k_assign(const float* __restrict__ data, const float* __restrict__ cen,
                         const int* __restrict__ cnt_inr, int* __restrict__ labels,
                         int* __restrict__ blockhist, const int* __restrict__ flag) {
    if (*flag) return;
    __shared__ float C[NUMC * FD];
    __shared__ int enough[NUMC];
    __shared__ int hist[NUMC];
    int tid = threadIdx.x;
    for (int e = tid; e < NUMC * FD; e += 256) C[e] = cen[e];
    if (tid < NUMC) { enough[tid] = (cnt_inr[tid] > 1); hist[tid] = 0; }
    __syncthreads();
    size_t j = (size_t)blockIdx.x * 256 + tid;
    float4 a = *(const float4*)(data + j * FD);
    float4 b = *(const float4*)(data + j * FD + 4);
    float x[8] = {a.x, a.y, a.z, a.w, b.x, b.y, b.z, b.w};
    int lab = -1;
    float dval = 1000.0f;
    for (int i = 0; i < NUMC; i++) {
        const float* c = &C[i * FD];
        float dx = __fsub_rn(x[0], c[0]);
        float dy = __fsub_rn(x[1], c[1]);
        float s  = __fadd_rn(__fmul_rn(dx, dx), __fmul_rn(dy, dy));
        float sp = __fsqrt_rn(s);
        if (sp <= 0.32f && enough[i]) {
            float t0 = __fadd_rn(__fsub_rn(x[0], c[0]), 1e-6f);
            float ss = __fmul_rn(t0, t0);
            #pragma unroll
            for (int f = 1; f < 8; f++) {
                float tf = __fadd_rn(__fsub_rn(x[f], c[f]), 1e-6f);
                ss = __fadd_rn(ss, __fmul_rn(tf, tf));
            }
            float D = __fsqrt_rn(ss);
            if (D < dval) { dval = D; lab = i; }
            else break;   // reference sets dval=0 -> frozen forever
        }
    }
    labels[j] = lab;
    if (lab >= 0) atomicAdd(&hist[lab], 1);
    __syncthreads();
    if (tid < NUMC) blockhist[tid * NBLK + blockIdx.x] = hist[tid];
}

// Per-cluster exclusive scan over the 2048 block counts.
// Folded k_base: the last block to finish computes cbase from ctot
// (threadfence + done-counter pattern), saving a 1-block launch per iter.
__global__ void k_scan(int* __restrict__ blockhist, int* __restrict__ ctot,
                       int* __restrict__ cbase, int* __restrict__ done,
                       const int* __restrict__ flag) {
    if (*flag) return;
    int c = blockIdx.x, tid = threadIdx.x;
    __shared__ int ts[256];
    __shared__ int amLast;
    int base = c * NBLK + tid * 8;
    int v[8], s = 0;
    #pragma unroll
    for (int u = 0; u < 8; u++) { v[u] = blockhist[base + u]; s += v[u]; }
    ts[tid] = s;
    __syncthreads();
    for (int off = 1; off < 256; off <<= 1) {
        int t = (tid >= off) ? ts[tid - off] : 0;
        __syncthreads();
        ts[tid] += t;
        __syncthreads();
    }
    int run = (tid == 0) ? 0 : ts[tid - 1];
    #pragma unroll
    for (int u = 0; u < 8; u++) { int t = v[u]; blockhist[base + u] = run; run += t; }
    if (tid == 255) {
        ctot[c] = run;
        __threadfence();
        amLast = (atomicAdd(done, 1) == NUMC - 1);
    }
    __syncthreads();
    if (amLast) {
        __threadfence();
        int val = (tid < NUMC) ? ctot[tid] : 0;
        ts[tid] = val;
        __syncthreads();
        for (int off = 1; off < NUMC; off <<= 1) {
            int t2 = (tid >= off) ? ts[tid - off] : 0;
            __syncthreads();
            ts[tid] += t2;
            __syncthreads();
        }
        if (tid < NUMC) cbase[tid] = ts[tid] - val;   // exclusive prefix
        if (tid == NUMC - 1) cbase[NUMC] = ts[tid];   // total assigned
        if (tid == 0) *done = 0;                      // reset for next iter
    }
}

// Fused stable scatter + feature-major materialization: thread j computes its
// stable position and writes its 8 features directly into the sorted columns.
__global__ void k_scatter(const float* __restrict__ data, const int* __restrict__ labels,
                          const int* __restrict__ blockhist, const int* __restrict__ cbase,
                          float* __restrict__ sorted, const int* __restrict__ flag) {
    if (*flag) return;
    __shared__ int sl[256];
    int tid = threadIdx.x;
    int j = blockIdx.x * 256 + tid;
    sl[tid] = labels[j];
    __syncthreads();
    int c = sl[tid];
    if (c >= 0) {
        int rank = 0;
        for (int t = 0; t < tid; t++) rank += (sl[t] == c);
        int pos = cbase[c] + blockhist[c * NBLK + blockIdx.x] + rank;
        float4 a = *(const float4*)(data + (size_t)j * FD);
        float4 b = *(const float4*)(data + (size_t)j * FD + 4);
        sorted[(size_t)0 * NPTS + pos] = a.x;
        sorted[(size_t)1 * NPTS + pos] = a.y;
        sorted[(size_t)2 * NPTS + pos] = a.z;
        sorted[(size_t)3 * NPTS + pos] = a.w;
        sorted[(size_t)4 * NPTS + pos] = b.x;
        sorted[(size_t)5 * NPTS + pos] = b.y;
        sorted[(size_t)6 * NPTS + pos] = b.z;
        sorted[(size_t)7 * NPTS + pos] = b.w;
    }
}

// Stage one 512-member chunk (all 8 features) into an LDS ring slot via async
// DMA: 16 x global_load_lds(16B/lane), no VGPR cost.
__device__ __forceinline__ void stage_chunk(const float* __restrict__ srt, int baseA,
                                            int t, int slot, float* sbuf, int lane) {
    const float* g0 = srt + (size_t)baseA + (size_t)t * CSZ + lane * 4;
    float* l0 = sbuf + slot * SLOTF;
    #pragma unroll
    for (int f = 0; f < FD; f++) {
        __builtin_amdgcn_global_load_lds(
            (const __attribute__((address_space(1))) void*)(g0 + (size_t)f * NPTS),
            (__attribute__((address_space(3))) void*)(l0 + f * FCOL),
            16, 0, 0);
        __builtin_amdgcn_global_load_lds(
            (const __attribute__((address_space(1))) void*)(g0 + (size_t)f * NPTS + 256),
            (__attribute__((address_space(3))) void*)(l0 + f * FCOL + 256),
            16, 0, 0);
    }
}

#define ADD4(v) { acc = __fadd_rn(acc, (v).x); acc = __fadd_rn(acc, (v).y); \
                  acc = __fadd_rn(acc, (v).z); acc = __fadd_rn(acc, (v).w); }

// Exact sequential fp32 segment sums: one wave per cluster. Continuous
// software pipeline across chunk boundaries: during chunk t's drain phase
// (b=96..127) the q-ring is refilled with chunk t+1's first 32 float4s, so
// the per-chunk cold-preload bubble disappears. Add order is identical to
// the per-chunk version (chunk t fully consumed in member order) -> bit-exact.
// NOTE (R3 post-mortem): q-ring depth 16 + unroll 16 REGRESSED 17% — halving
// the unroll doubles loop-control/waitcnt frequency on a single in-order wave
// with no co-resident waves to hide it. Keep depth 32 / unroll 32.
__global__ void __launch_bounds__(64) k_sums(const float* __restrict__ sorted,
                       const int* __restrict__ cbase, const int* __restrict__ ctot,
                       float* __restrict__ sums, const int* __restrict__ flag) {
    if (*flag) return;
    __shared__ float sbuf[RING * SLOTF];
    int c = blockIdx.x;
    int lane = threadIdx.x;
    int m = ctot[c], base = cbase[c];
    float acc = 0.0f;
    const float* col = sorted + (size_t)lane * NPTS + base;   // lane<8 chain column

    int A = (4 - (base & 3)) & 3;          // scalar prologue to 16B alignment
    if (A > m) A = m;
    if (lane < FD)
        for (int k = 0; k < A; k++) acc = __fadd_rn(acc, col[k]);

    int baseA = base + A;
    int nch = (m - A) / CSZ;               // full 512-member chunks

    int pre = nch < RING ? nch : RING;
    for (int t = 0; t < pre; t++) stage_chunk(sorted, baseA, t, t, sbuf, lane);

    float4 q[32];
    if (nch > 0) {
        // wait for chunk 0's DMA, preload its first 32 float4s into the ring
        if (nch >= 3) { WAITVM(32); } else if (nch == 2) { WAITVM(16); } else { WAITVM(0); }
        if (lane < FD) {
            const float4* lv0 = (const float4*)(sbuf + lane * FCOL);
            #pragma unroll
            for (int d = 0; d < 32; d++) q[d] = lv0[d];
        }
    }

    int slot = 0;
    for (int t = 0; t < nch; t++) {
        if (t >= 1 && t + 2 < nch)
            stage_chunk(sorted, baseA, t + 2, slot == 0 ? 2 : slot - 1, sbuf, lane);
        const float4* lv = (const float4*)(sbuf + slot * SLOTF + lane * FCOL);
        if (lane < FD) {
            #pragma unroll 32
            for (int b = 0; b < 96; b++) {
                float4 v = q[b & 31];
                ADD4(v);
                q[b & 31] = lv[b + 32];
            }
        }
        int nslot = (slot == RING - 1) ? 0 : slot + 1;
        if (t + 1 < nch) {
            // chunk t+1's DMA must be complete before reading its LDS slot:
            // outstanding beyond t+1 is chunk t+2 (16 loads) if staged.
            if (t + 2 < nch) { WAITVM(16); } else { WAITVM(0); }
            if (lane < FD) {
                const float4* lvn = (const float4*)(sbuf + nslot * SLOTF + lane * FCOL);
                #pragma unroll
                for (int b = 96; b < 128; b++) {
                    float4 v = q[b & 31];
                    ADD4(v);
                    q[b & 31] = lvn[b - 96];
                }
            }
        } else {
            if (lane < FD) {
                #pragma unroll
                for (int b = 96; b < 128; b++) { float4 v = q[b & 31]; ADD4(v); }
            }
        }
        slot = nslot;
    }

    // tail: members [A + nch*CSZ, m) from global, float4 depth-16 pipe (aligned)
    if (lane < FD) {
        int start = A + nch * CSZ;
        int rem = m - start;
        const float* tcol = col + start;
        int tv = rem >> 2;
        const float4* tvp = (const float4*)tcol;
        float4 tb[16];
        #pragma unroll
        for (int d = 0; d < 16; d++) if (d < tv) tb[d] = tvp[d];
        int u = 0;
        for (; u + 32 <= tv; u += 16) {
            #pragma unroll
            for (int d = 0; d < 16; d++) {
                float4 v = tb[d];
                ADD4(v);
                tb[d] = tvp[u + 16 + d];
            }
        }
        #pragma unroll
        for (int d = 0; d < 16; d++) {
            if (u + d < tv) {
                float4 v = tb[d];
                ADD4(v);
                if (u + 16 + d < tv) tb[d] = tvp[u + 16 + d];
            }
        }
        u += 16;
        #pragma unroll
        for (int d = 0; d < 16; d++) {
            if (u + d < tv) { float4 v = tb[d]; ADD4(v); }
        }
        for (int k = tv << 2; k < rem; k++) acc = __fadd_rn(acc, tcol[k]);
        sums[c * FD + lane] = acc;
    }
}

// Center update + convergence flag (1 block); also zeroes cnt_inr for the
// next iteration (replaces the separate k_zero launch).
__global__ void k_update(float* __restrict__ cen, const float* __restrict__ sums,
                         const int* __restrict__ ctot, int* __restrict__ flag,
                         int* __restrict__ cnt_inr) {
    if (*flag) return;
    __shared__ float red[256];
    int tid = threadIdx.x;
    if (tid < NUMC) cnt_inr[tid] = 0;
    float sq = 0.0f;
    float newv[4];
    int   eidx[4];
    int ne = 0;
    for (int e = tid; e < NUMC * FD; e += 256) {
        int c = e >> 3;
        float oldv = cen[e];
        float cntf = (float)ctot[c];
        float mean = __fdiv_rn(sums[e], fmaxf(cntf, 1.0f));
        float nc = (cntf > 0.0f) ? mean : oldv;
        float d = __fsub_rn(nc, oldv);
        sq = __fadd_rn(sq, __fmul_rn(d, d));
        newv[ne] = nc; eidx[ne] = e; ne++;
    }
    red[tid] = sq;
    __syncthreads();
    for (int off = 128; off > 0; off >>= 1) {
        if (tid < off) red[tid] += red[tid + off];
        __syncthreads();
    }
    for (int u = 0; u < ne; u++) cen[eidx[u]] = newv[u];
    if (tid == 0) {
        float diff = __fsqrt_rn(red[0]);
        if (diff < 1e-4f) *flag = 1;
    }
}

// Finalize: labels staged as int32 in d_out[0..N); convert to float, append centers.
__global__ void k_finish(float* __restrict__ out, const float* __restrict__ cen) {
    size_t i = (size_t)blockIdx.x * 256 + threadIdx.x;
    if (i < NPTS) {
        int v = ((const int*)out)[i];
        out[i] = (float)v;
    } else if (i < NPTS + NUMC * FD) {
        out[i] = cen[i - NPTS];
    }
}

extern "C" void kernel_launch(void* const* d_in, const int* in_sizes, int n_in,
                              void* d_out, int out_size, void* d_ws, size_t ws_size,
                              hipStream_t stream) {
    const float* data = (const float*)d_in[0];
    const float* cen0 = (const float*)d_in[1];
    float* out = (float*)d_out;
    char* ws = (char*)d_ws;

    float* wcen   = (float*)(ws + 0);
    int*   flag   = (int*)(ws + 4096);
    int*   cntinr = (int*)(ws + 8192);
    int*   ctot   = (int*)(ws + 8704);
    int*   cbase  = (int*)(ws + 9216);    // 129 ints
    float* sums   = (float*)(ws + 10240);
    int*   done   = (int*)(ws + 14336);
    int*   bh     = (int*)(ws + 16384);
    float* sorted = (float*)(ws + 16384 + (size_t)NUMC * NBLK * 4);
    int*   labels = (int*)d_out;   // staged as int32, converted by k_finish

    k_init<<<4, 256, 0, stream>>>(cen0, wcen, flag, cntinr, done);
    for (int it = 0; it < ITERS; ++it) {
        k_count  <<<NBLK, 256, 0, stream>>>(data, wcen, cntinr, flag);
        k_assign <<<NBLK, 256, 0, stream>>>(data, wcen, cntinr, labels, bh, flag);
        k_scan   <<<NUMC, 256, 0, stream>>>(bh, ctot, cbase, done, flag);
        k_scatter<<<NBLK, 256, 0, stream>>>(data, labels, bh, cbase, sorted, flag);
        k_sums   <<<NUMC, 64, 0, stream>>>(sorted, cbase, ctot, sums, flag);
        k_update <<<1, 256, 0, stream>>>(wcen, sums, ctot, flag, cntinr);
    }
    k_finish<<<(NPTS + NUMC * FD + 255) / 256, 256, 0, stream>>>(out, wcen);
}